// Round 15
// baseline (531.619 us; speedup 1.0000x reference)
//
#include <hip/hip_runtime.h>
#include <hip/hip_bf16.h>
#include <stdint.h>

// Transformer block: B=8, T=2048, C=1024, fp32 in/out, bf16 MFMA internally.
// Round 15: big GEMMs on gemm128d — 128x128 tile, BK=64 (3-bit XOR swizzle,
// 0 conflicts), DOUBLE-buffered 64 KB LDS => 2 blocks/CU (m97/m114 cross-
// block overlap: one block's vmcnt/barrier drain hides under the other's
// MFMA). Unpinned 2-barrier loop, stage(t+1) issued at body top.
// S/AV (gemm128 BK32, 4 blocks/CU), triangular softmax, rmsnorm, wcast,
// bf16 x_mid path all unchanged from round 13 (best measured, 499.7us).

#define C_DIM 1024
#define T_DIM 2048
#define B_DIM 8

typedef float f32x4 __attribute__((ext_vector_type(4)));
typedef __bf16 bf16x8 __attribute__((ext_vector_type(8)));

typedef const __attribute__((address_space(1))) void gvoid_t;
typedef __attribute__((address_space(3))) void lvoid_t;

__device__ __forceinline__ void gload_lds16(const void* g, void* l) {
    __builtin_amdgcn_global_load_lds((gvoid_t*)g, (lvoid_t*)l, 16, 0, 0);
}

__device__ __forceinline__ unsigned short f2bf_bits(float f) {
    __hip_bfloat16 h = __float2bfloat16(f);
    return *reinterpret_cast<unsigned short*>(&h);
}

// Bijective XCD-chunked remap (m204)
__device__ __forceinline__ void xcd_remap(int& bx, int& by, int& bz) {
    const int gx = gridDim.x, gy = gridDim.y;
    const int nwg = gx * gy * (int)gridDim.z;
    const int orig = bx + gx * (by + gy * bz);
    const int q = nwg >> 3, r = nwg & 7;
    const int xcd = orig & 7, pos = orig >> 3;
    const int neu = (xcd < r ? xcd * (q + 1) : r * (q + 1) + (xcd - r) * q) + pos;
    bx = neu % gx;
    const int t = neu / gx;
    by = t % gy;
    bz = t / gy;
}

// ===========================================================================
// gemm128d: 128x128 tile, BK=64, 4 waves (2Mx2N), double-buffered 64 KB LDS
// (=> 2 blocks/CU). LDS rows 128B; granule g: row=g>>3, slot=g&7 holds global
// chunk (g&7)^(row&7) (involution via pre-swizzled source). Per K-tile:
// { stage(t+1)->buf^1 | 16 ds_read_b128 | 32 MFMA (compiler-interleaved) |
//   lgkmcnt(0) | vmcnt(0) | s_barrier }.  No sched_barrier anywhere.
// EPI: 0 bf16; 3 bf16 silu; 5 bf16 transposed store vT[B][C][T];
//      8 xmid = R(fp32)+acc -> bf16;  9 out = Rb(bf16)+acc -> fp32.
// ===========================================================================
template<int EPI>
__global__ __launch_bounds__(256, 2)
void gemm128d(const __hip_bfloat16* A, const __hip_bfloat16* Bt,
              void* Cout, const void* Rv,
              int K, int lda, int ldb, int ldc)
{
    int bx = blockIdx.x, by = blockIdx.y, bz = blockIdx.z;
    xcd_remap(bx, by, bz);

    const int tid  = threadIdx.x;
    const int lane = tid & 63, wave = tid >> 6;
    const int l15  = lane & 15, l4 = lane >> 4;
    const int wr   = wave >> 1, wc = wave & 1;
    const int m0   = by * 128, n0 = bx * 128;

    __shared__ __align__(16) char lds_[65536];   // buf: [A 16K | B 16K] x2

    const int NT = K >> 6;

    // staging: inst i in 0..3, granule g = i*256 + tid; row = i*32 + (tid>>3),
    // slot = tid&7, global chunk = slot ^ (row&7) = (tid&7) ^ ((tid>>3)&7).
    const int srow = tid >> 3;
    const int schk = (tid & 7) ^ (srow & 7);
    const __hip_bfloat16* Ag = A + (long long)(m0 + srow) * lda + schk * 8;
    const __hip_bfloat16* Bg = Bt + (long long)(n0 + srow) * ldb + schk * 8;
    // LDS dest for inst i: base + (i*256 + wave*64)*16 + lane*16 (linear)
    char* ldsw = lds_ + (wave * 64) * 16;

    // read offsets: byte = l15*128 + ((chunk ^ (l15&7))<<4), chunk = ks*4+l4
    const int offk0 = l15 * 128 + (((l4)     ^ (l15 & 7)) << 4);
    const int offk1 = l15 * 128 + (((4 + l4) ^ (l15 & 7)) << 4);

    f32x4 acc[4][4];
#pragma unroll
    for (int i = 0; i < 4; ++i)
#pragma unroll
        for (int j = 0; j < 4; ++j) acc[i][j] = (f32x4){0.f, 0.f, 0.f, 0.f};

    auto stage = [&](int buf, int t) {
        char* ab = ldsw + buf * 32768;
        char* bb = ab + 16384;
        const long long koff = (long long)t * 64;
#pragma unroll
        for (int i = 0; i < 4; ++i) {
            gload_lds16(Ag + koff + (long long)i * 32 * lda, ab + i * 4096);
            gload_lds16(Bg + koff + (long long)i * 32 * ldb, bb + i * 4096);
        }
    };

    // prologue: tile 0 -> buf0
    stage(0, 0);
    asm volatile("s_waitcnt vmcnt(0)" ::: "memory");
    __builtin_amdgcn_s_barrier();

    for (int t = 0; t < NT; ++t) {
        const int buf = t & 1;
        if (t + 1 < NT) stage(buf ^ 1, t + 1);

        const char* ab = lds_ + buf * 32768;
        const char* bb = ab + 16384;
        bf16x8 aR[4][2], bR[4][2];
#pragma unroll
        for (int mf = 0; mf < 4; ++mf) {
            const char* p = ab + (wr * 64 + mf * 16) * 128;
            aR[mf][0] = *(const bf16x8*)(p + offk0);
            aR[mf][1] = *(const bf16x8*)(p + offk1);
        }
#pragma unroll
        for (int nf = 0; nf < 4; ++nf) {
            const char* p = bb + (wc * 64 + nf * 16) * 128;
            bR[nf][0] = *(const bf16x8*)(p + offk0);
            bR[nf][1] = *(const bf16x8*)(p + offk1);
        }
        __builtin_amdgcn_s_setprio(1);
#pragma unroll
        for (int mf = 0; mf < 4; ++mf)
#pragma unroll
            for (int nf = 0; nf < 4; ++nf)
#pragma unroll
                for (int ks = 0; ks < 2; ++ks)
                    acc[mf][nf] = __builtin_amdgcn_mfma_f32_16x16x32_bf16(
                        aR[mf][ks], bR[nf][ks], acc[mf][nf], 0, 0, 0);
        __builtin_amdgcn_s_setprio(0);

        asm volatile("s_waitcnt lgkmcnt(0)" ::: "memory");
        asm volatile("s_waitcnt vmcnt(0)" ::: "memory");
        __builtin_amdgcn_s_barrier();
    }

    // epilogue: row = m0 + wr*64 + mf*16 + l4*4 + r; col = n0 + wc*64 + nf*16 + l15
#pragma unroll
    for (int mf = 0; mf < 4; ++mf) {
        const int rbase = m0 + wr * 64 + mf * 16 + l4 * 4;
#pragma unroll
        for (int nf = 0; nf < 4; ++nf) {
            const int col = n0 + wc * 64 + nf * 16 + l15;
#pragma unroll
            for (int r = 0; r < 4; ++r) {
                const float v = acc[mf][nf][r];
                const int row = rbase + r;
                if constexpr (EPI == 5) {
                    ((__hip_bfloat16*)Cout)[((long long)(row >> 11) * C_DIM + col) * T_DIM
                                            + (row & 2047)] = __float2bfloat16(v);
                } else {
                    const long long idx = (long long)row * ldc + col;
                    if constexpr (EPI == 0) {
                        ((__hip_bfloat16*)Cout)[idx] = __float2bfloat16(v);
                    } else if constexpr (EPI == 3) {
                        const float s = v / (1.f + __expf(-v));
                        ((__hip_bfloat16*)Cout)[idx] = __float2bfloat16(s);
                    } else if constexpr (EPI == 8) {
                        const float xr = ((const float*)Rv)[idx];
                        ((__hip_bfloat16*)Cout)[idx] = __float2bfloat16(v + xr);
                    } else { // EPI == 9
                        const float xr =
                            __bfloat162float(((const __hip_bfloat16*)Rv)[idx]);
                        ((float*)Cout)[idx] = v + xr;
                    }
                }
            }
        }
    }
}

// ===========================================================================
// gemm128 (round-4 core, r13-verified): BK=32, 4 waves, dbuf 32 KiB,
// 4-chunk swz, ~4 blocks/CU.  EPI: 0 bf16; 4 bf16*scale.
// CMODE: 1 causal block skip; 2 causal K clip.  Used for S and AV.
// ===========================================================================
template<int EPI, int CMODE>
__global__ __launch_bounds__(256)
void gemm128(const __hip_bfloat16* A, const __hip_bfloat16* Bt,
             void* Cout, int K, int lda, int ldb, int ldc,
             long long sA, long long sB, long long sC, float scale)
{
    int bx = blockIdx.x, by = blockIdx.y, bz = blockIdx.z;
    xcd_remap(bx, by, bz);
    if constexpr (CMODE == 1) { if (bx > by) return; }

    const int tid  = threadIdx.x;
    const int lane = tid & 63, wave = tid >> 6;
    const int l15  = lane & 15, l4 = lane >> 4;
    const int wr   = wave >> 1, wc = wave & 1;
    const int m0   = by * 128, n0 = bx * 128;
    const int z    = bz;

    A  += (long long)z * sA;
    Bt += (long long)z * sB;

    __shared__ __align__(16) short As[2][128 * 32];
    __shared__ __align__(16) short Bs[2][128 * 32];

    int kmax = K;
    if constexpr (CMODE == 2) { int km = m0 + 128; kmax = km < K ? km : K; }

    f32x4 acc[4][4];
#pragma unroll
    for (int i = 0; i < 4; ++i)
#pragma unroll
        for (int j = 0; j < 4; ++j) acc[i][j] = (f32x4){0.f, 0.f, 0.f, 0.f};

    const int srow  = wave * 32 + (lane >> 2);
    const int sbyte = (((lane & 3) ^ ((lane >> 2) & 3))) << 4;
    const char* Ag = (const char*)(A  + (long long)(m0 + srow) * lda) + sbyte;
    const char* Bg = (const char*)(Bt + (long long)(n0 + srow) * ldb) + sbyte;
    const long long astep = (long long)16 * lda * 2;
    const long long bstep = (long long)16 * ldb * 2;
    char* AsW[2] = {(char*)As[0] + wave * 2048, (char*)As[1] + wave * 2048};
    char* BsW[2] = {(char*)Bs[0] + wave * 2048, (char*)Bs[1] + wave * 2048};

    auto stage = [&](int buf, int k0) {
        const char* ag = Ag + (long long)k0 * 2;
        const char* bg = Bg + (long long)k0 * 2;
        gload_lds16(ag,         AsW[buf]);
        gload_lds16(ag + astep, AsW[buf] + 1024);
        gload_lds16(bg,         BsW[buf]);
        gload_lds16(bg + bstep, BsW[buf] + 1024);
    };

    const int cs16 = ((l4 ^ (l15 & 3)) << 4);

    stage(0, 0);
    __syncthreads();

    for (int k0 = 0; k0 < kmax; k0 += 32) {
        const int buf = (k0 >> 5) & 1;
        if (k0 + 32 < kmax) stage(buf ^ 1, k0 + 32);

        const char* Ac = (const char*)As[buf];
        const char* Bc = (const char*)Bs[buf];
        bf16x8 af[4], bfr[4];
#pragma unroll
        for (int mi = 0; mi < 4; ++mi) {
            int row = wr * 64 + mi * 16 + l15;
            af[mi] = *(const bf16x8*)(Ac + row * 64 + cs16);
        }
#pragma unroll
        for (int ni = 0; ni < 4; ++ni) {
            int col = wc * 64 + ni * 16 + l15;
            bfr[ni] = *(const bf16x8*)(Bc + col * 64 + cs16);
        }
#pragma unroll
        for (int mi = 0; mi < 4; ++mi)
#pragma unroll
            for (int ni = 0; ni < 4; ++ni)
                acc[mi][ni] = __builtin_amdgcn_mfma_f32_16x16x32_bf16(
                    af[mi], bfr[ni], acc[mi][ni], 0, 0, 0);

        __syncthreads();
    }

    const long long cbase = (long long)z * sC;
#pragma unroll
    for (int mi = 0; mi < 4; ++mi) {
        const int rbase = m0 + wr * 64 + mi * 16 + l4 * 4;
#pragma unroll
        for (int ni = 0; ni < 4; ++ni) {
            const int col = n0 + wc * 64 + ni * 16 + l15;
#pragma unroll
            for (int r = 0; r < 4; ++r) {
                const long long idx = cbase + (long long)(rbase + r) * ldc + col;
                const float v = acc[mi][ni][r];
                if constexpr (EPI == 0) {
                    ((__hip_bfloat16*)Cout)[idx] = __float2bfloat16(v);
                } else { // EPI == 4
                    ((__hip_bfloat16*)Cout)[idx] = __float2bfloat16(v * scale);
                }
            }
        }
    }
}

// ---------------------------------------------------------------------------
// RMSNorm: one block per row of C_DIM; input fp32 or bf16, output bf16.
// ---------------------------------------------------------------------------
template<bool BF16IN>
__global__ __launch_bounds__(256)
void rmsnorm_kernel(const void* __restrict__ xin, const float* __restrict__ g,
                    __hip_bfloat16* __restrict__ out)
{
    const long long row = blockIdx.x;
    const int tid = threadIdx.x;
    float e0, e1, e2, e3;
    if constexpr (BF16IN) {
        const ushort4 u = ((const ushort4*)((const __hip_bfloat16*)xin + row * C_DIM))[tid];
        e0 = __uint_as_float((unsigned)u.x << 16);
        e1 = __uint_as_float((unsigned)u.y << 16);
        e2 = __uint_as_float((unsigned)u.z << 16);
        e3 = __uint_as_float((unsigned)u.w << 16);
    } else {
        const float4 v = ((const float4*)((const float*)xin + row * C_DIM))[tid];
        e0 = v.x; e1 = v.y; e2 = v.z; e3 = v.w;
    }
    float ss = e0 * e0 + e1 * e1 + e2 * e2 + e3 * e3;
#pragma unroll
    for (int off = 32; off; off >>= 1) ss += __shfl_xor(ss, off);
    __shared__ float red[4];
    if ((tid & 63) == 0) red[tid >> 6] = ss;
    __syncthreads();
    ss = red[0] + red[1] + red[2] + red[3];
    const float sc = rsqrtf(ss * (1.0f / C_DIM) + 1e-6f);
    const float4 gv = ((const float4*)g)[tid];
    ushort4 u;
    u.x = f2bf_bits(e0 * sc * gv.x);
    u.y = f2bf_bits(e1 * sc * gv.y);
    u.z = f2bf_bits(e2 * sc * gv.z);
    u.w = f2bf_bits(e3 * sc * gv.w);
    *(ushort4*)(out + row * C_DIM + tid * 4) = u;
}

// ---------------------------------------------------------------------------
// Causal softmax, IN PLACE on bf16 S [B,T,T], triangular (cols < AV K-clip).
// ---------------------------------------------------------------------------
__global__ __launch_bounds__(256)
void softmax_causal(__hip_bfloat16* __restrict__ SP)
{
    const int i = blockIdx.x, b = blockIdx.y;
    __hip_bfloat16* row = SP + ((long long)b * T_DIM + i) * T_DIM;
    const int tid = threadIdx.x;
    const int jbase = tid * 8;
    const int kmax = ((i >> 7) + 1) << 7;
    const bool act = jbase < kmax;

    float v[8];
    if (act) {
        uint4 raw = ((const uint4*)row)[tid];
        const unsigned w[4] = {raw.x, raw.y, raw.z, raw.w};
#pragma unroll
        for (int c = 0; c < 4; ++c) {
            v[2 * c]     = __uint_as_float(w[c] << 16);
            v[2 * c + 1] = __uint_as_float(w[c] & 0xFFFF0000u);
        }
#pragma unroll
        for (int e = 0; e < 8; ++e)
            if (jbase + e > i) v[e] = -1e30f;
    } else {
#pragma unroll
        for (int e = 0; e < 8; ++e) v[e] = -1e30f;
    }

    float m = v[0];
#pragma unroll
    for (int e = 1; e < 8; ++e) m = fmaxf(m, v[e]);
#pragma unroll
    for (int off = 32; off; off >>= 1) m = fmaxf(m, __shfl_xor(m, off));
    __shared__ float redm[4], reds[4];
    if ((tid & 63) == 0) redm[tid >> 6] = m;
    __syncthreads();
    m = fmaxf(fmaxf(redm[0], redm[1]), fmaxf(redm[2], redm[3]));

    float e8[8];
    float s = 0.f;
#pragma unroll
    for (int e = 0; e < 8; ++e) { e8[e] = __expf(v[e] - m); s += e8[e]; }
#pragma unroll
    for (int off = 32; off; off >>= 1) s += __shfl_xor(s, off);
    if ((tid & 63) == 0) reds[tid >> 6] = s;
    __syncthreads();
    s = reds[0] + reds[1] + reds[2] + reds[3];
    const float inv = 1.f / s;

    if (act) {
        uint4 outw;
        unsigned o[4];
#pragma unroll
        for (int c = 0; c < 4; ++c) {
            unsigned lo = f2bf_bits(e8[2 * c] * inv);
            unsigned hi = f2bf_bits(e8[2 * c + 1] * inv);
            o[c] = lo | (hi << 16);
        }
        outw.x = o[0]; outw.y = o[1]; outw.z = o[2]; outw.w = o[3];
        ((uint4*)row)[tid] = outw;
    }
}

// ---------------------------------------------------------------------------
// Weight cast + transpose: in fp32 [K,N] -> out bf16 [N,K]
// ---------------------------------------------------------------------------
__global__ __launch_bounds__(256)
void wcast_t(const float* __restrict__ in, __hip_bfloat16* __restrict__ out,
             int K, int N)
{
    __shared__ float t[32][33];
    const int n0 = blockIdx.x * 32, k0 = blockIdx.y * 32;
    const int tx = threadIdx.x, ty = threadIdx.y;
#pragma unroll
    for (int r = ty; r < 32; r += 8)
        t[r][tx] = in[(long long)(k0 + r) * N + n0 + tx];
    __syncthreads();
#pragma unroll
    for (int r = ty; r < 32; r += 8)
        out[(long long)(n0 + r) * K + k0 + tx] = __float2bfloat16(t[tx][r]);
}

// ---------------------------------------------------------------------------
extern "C" void kernel_launch(void* const* d_in, const int* in_sizes, int n_in,
                              void* d_out, int out_size, void* d_ws, size_t ws_size,
                              hipStream_t stream)
{
    const float* x      = (const float*)d_in[0];
    const float* w_qkv  = (const float*)d_in[1];
    const float* w_proj = (const float*)d_in[2];
    const float* w1     = (const float*)d_in[3];
    const float* w2     = (const float*)d_in[4];
    const float* g1     = (const float*)d_in[5];
    const float* g2     = (const float*)d_in[6];
    float* out = (float*)d_out;
    char* ws = (char*)d_ws;

    const size_t SP_off = 0;                       // S/P bf16 [8,2048,2048] 64MiB
    const size_t h_off  = 0;                       // h bf16 (before S exists)
    const size_t u_off  = 0;                       // u bf16 (after P dead)
    const size_t q_off  = 67108864ull;             // q bf16 -> h2
    const size_t k_off  = 100663296ull;            // k bf16 -> av
    const size_t vT_off = 134217728ull;            // vT bf16 -> x_mid bf16 (after AV)
    const size_t wq_off = 167772160ull;            // 6.29MB
    const size_t wp_off = wq_off + 6291456ull;     // 2.10MB
    const size_t w1_off = wp_off + 2097152ull;     // 4.19MB
    const size_t w2_off = w1_off + 4194304ull;     // 4.19MB
    const size_t NEED   = w2_off + 4194304ull;     // 176 MiB

    if (ws_size < NEED) return;  // guard: fail absmax instead of faulting

    auto bf = [&](size_t off) { return (__hip_bfloat16*)(ws + off); };

    // 1. weights -> bf16 [N,K]
    wcast_t<<<dim3(96, 32), dim3(32, 8), 0, stream>>>(w_qkv,  bf(wq_off), 1024, 3072);
    wcast_t<<<dim3(32, 32), dim3(32, 8), 0, stream>>>(w_proj, bf(wp_off), 1024, 1024);
    wcast_t<<<dim3(64, 32), dim3(32, 8), 0, stream>>>(w1,     bf(w1_off), 1024, 2048);
    wcast_t<<<dim3(32, 64), dim3(32, 8), 0, stream>>>(w2,     bf(w2_off), 2048, 1024);

    // 2. h = rmsnorm(x, g1)
    rmsnorm_kernel<false><<<16384, 256, 0, stream>>>(x, g1, bf(h_off));

    // 3a. q = h @ Wq
    gemm128d<0><<<dim3(8, 128, 1), 256, 0, stream>>>(
        bf(h_off), bf(wq_off), bf(q_off), nullptr, 1024, 1024, 1024, 1024);
    // 3b. k = h @ Wk
    gemm128d<0><<<dim3(8, 128, 1), 256, 0, stream>>>(
        bf(h_off), bf(wq_off) + 1024 * 1024, bf(k_off), nullptr,
        1024, 1024, 1024, 1024);
    // 3c. vT = (h @ Wv)^T
    gemm128d<5><<<dim3(8, 128, 1), 256, 0, stream>>>(
        bf(h_off), bf(wq_off) + 2 * 1024 * 1024, bf(vT_off), nullptr,
        1024, 1024, 1024, 2048);

    // 4. S = q @ k^T * 1/32  (128-tile, causal block skip)
    gemm128<4, 1><<<dim3(16, 16, 8), 256, 0, stream>>>(
        bf(q_off), bf(k_off), bf(SP_off),
        1024, 1024, 1024, 2048,
        (long long)T_DIM * C_DIM, (long long)T_DIM * C_DIM, (long long)T_DIM * T_DIM,
        0.03125f);

    // 5. P = causal softmax(S), in place, triangular
    softmax_causal<<<dim3(2048, 8), 256, 0, stream>>>(bf(SP_off));

    // 6. av = P @ V  (128-tile, K clipped at diagonal)
    gemm128<0, 2><<<dim3(8, 16, 8), 256, 0, stream>>>(
        bf(SP_off), bf(vT_off), bf(k_off) /*av*/,
        2048, 2048, 2048, 1024,
        (long long)T_DIM * T_DIM, (long long)C_DIM * T_DIM, (long long)T_DIM * C_DIM,
        1.f);

    // 7. x_mid(bf16) = x(fp32) + av @ w_proj   (-> vT region, vT dead)
    gemm128d<8><<<dim3(8, 128, 1), 256, 0, stream>>>(
        bf(k_off) /*av*/, bf(wp_off), bf(vT_off) /*x_mid*/, x,
        1024, 1024, 1024, 1024);

    // 8. h2 = rmsnorm(x_mid bf16, g2)   (-> q region)
    rmsnorm_kernel<true><<<16384, 256, 0, stream>>>(bf(vT_off), g2, bf(q_off));

    // 9. u = silu(h2 @ w1)   (-> SP region, dead)
    gemm128d<3><<<dim3(16, 128, 1), 256, 0, stream>>>(
        bf(q_off), bf(w1_off), bf(u_off), nullptr,
        1024, 1024, 1024, 2048);

    // 10. out(fp32) = x_mid(bf16) + u @ w2
    gemm128d<9><<<dim3(8, 128, 1), 256, 0, stream>>>(
        bf(u_off), bf(w2_off), out, bf(vT_off) /*x_mid*/,
        2048, 2048, 2048, 1024);
}

// Round 16
// 498.663 us; speedup vs baseline: 1.0661x; 1.0661x over previous
//
#include <hip/hip_runtime.h>
#include <hip/hip_bf16.h>
#include <stdint.h>

// Transformer block: B=8, T=2048, C=1024, fp32 in/out, bf16 MFMA internally.
// Round 16: exact revert to round-13 (best measured, 499.7us). Nine GEMM
// core variants over rounds 4-15 all land at 700-760 TF for these K=1024/2048
// shapes (~90% of the documented same-shape full-stack ceiling, m248: 848 TF).
// Config: q via 32x32 core, k/v/proj/FFN via 256^2 unpinned 2-phase core,
// S/AV via 128^2 BK32 dbuf core, triangular softmax, bf16 x_mid path.

#define C_DIM 1024
#define T_DIM 2048
#define B_DIM 8

typedef float f32x4  __attribute__((ext_vector_type(4)));
typedef float f32x16 __attribute__((ext_vector_type(16)));
typedef __bf16 bf16x8 __attribute__((ext_vector_type(8)));

typedef const __attribute__((address_space(1))) void gvoid_t;
typedef __attribute__((address_space(3))) void lvoid_t;

__device__ __forceinline__ void gload_lds16(const void* g, void* l) {
    __builtin_amdgcn_global_load_lds((gvoid_t*)g, (lvoid_t*)l, 16, 0, 0);
}

__device__ __forceinline__ unsigned short f2bf_bits(float f) {
    __hip_bfloat16 h = __float2bfloat16(f);
    return *reinterpret_cast<unsigned short*>(&h);
}

// Bijective XCD-chunked remap (m204)
__device__ __forceinline__ void xcd_remap(int& bx, int& by, int& bz) {
    const int gx = gridDim.x, gy = gridDim.y;
    const int nwg = gx * gy * (int)gridDim.z;
    const int orig = bx + gx * (by + gy * bz);
    const int q = nwg >> 3, r = nwg & 7;
    const int xcd = orig & 7, pos = orig >> 3;
    const int neu = (xcd < r ? xcd * (q + 1) : r * (q + 1) + (xcd - r) * q) + pos;
    bx = neu % gx;
    const int t = neu / gx;
    by = t % gy;
    bz = t / gy;
}

// ===========================================================================
// 256x256, 16x16x32 fragments, unpinned single-sync body.
// ===========================================================================
#define RD_A(dst, buf, hq) do { \
    _Pragma("unroll") \
    for (int mf_ = 0; mf_ < 4; ++mf_) { \
        const char* p_ = lds + (buf)*32768 + wrb + (hq)*8192 + mf_*2048; \
        dst[mf_][0] = *(const bf16x8*)(p_ + offk0); \
        dst[mf_][1] = *(const bf16x8*)(p_ + offk1); \
    } \
} while(0)

#define RD_B(dst, buf, nh) do { \
    _Pragma("unroll") \
    for (int n2_ = 0; n2_ < 2; ++n2_) { \
        const char* p_ = lds + 65536 + (buf)*32768 + wcb + ((nh)*2 + n2_)*2048; \
        dst[n2_][0] = *(const bf16x8*)(p_ + offk0); \
        dst[n2_][1] = *(const bf16x8*)(p_ + offk1); \
    } \
} while(0)

#define MMQ(aS, bS, Mh, Nh) do { \
    _Pragma("unroll") \
    for (int m4_ = 0; m4_ < 4; ++m4_) \
    _Pragma("unroll") \
    for (int n2_ = 0; n2_ < 2; ++n2_) \
    _Pragma("unroll") \
    for (int ks_ = 0; ks_ < 2; ++ks_) \
        acc[(Mh)*4 + m4_][(Nh)*2 + n2_] = __builtin_amdgcn_mfma_f32_16x16x32_bf16( \
            aS[m4_][ks_], bS[n2_][ks_], acc[(Mh)*4 + m4_][(Nh)*2 + n2_], 0, 0, 0); \
} while(0)

#define STA(buf, half, kt) do { \
    const int go_ = aoff + (half)*128*lda + (kt)*64; \
    char* lp_ = ldsw + (buf)*32768 + (half)*16384; \
    gload_lds16(A + go_,            lp_); \
    gload_lds16(A + go_ + 64*lda,   lp_ + 8192); \
} while(0)
#define STB(buf, half, kt) do { \
    const int go_ = boff + (half)*128*ldb + (kt)*64; \
    char* lp_ = ldsw + 65536 + (buf)*32768 + (half)*16384; \
    gload_lds16(Bt + go_,           lp_); \
    gload_lds16(Bt + go_ + 64*ldb,  lp_ + 8192); \
} while(0)

#define TILE_BODY(t, STG) do { \
    const int buf_ = (t) & 1; \
    bf16x8 a0[4][2], a1[4][2], b0v[2][2], b1v[2][2]; \
    RD_A(a0, buf_, 0); RD_A(a1, buf_, 1); \
    RD_B(b0v, buf_, 0); RD_B(b1v, buf_, 1); \
    __builtin_amdgcn_s_setprio(1); \
    MMQ(a0, b0v, 0, 0); MMQ(a0, b1v, 0, 1); \
    MMQ(a1, b0v, 1, 0); MMQ(a1, b1v, 1, 1); \
    __builtin_amdgcn_s_setprio(0); \
    asm volatile("s_waitcnt lgkmcnt(0)" ::: "memory"); \
    asm volatile("s_waitcnt vmcnt(0)" ::: "memory"); \
    __builtin_amdgcn_s_barrier(); \
    if (STG) { STB(buf_,0,(t)+2); STB(buf_,1,(t)+2); \
               STA(buf_,0,(t)+2); STA(buf_,1,(t)+2); } \
} while(0)

// EPI: 0 bf16; 3 bf16 silu; 5 bf16 transposed store into vT[B][C][T];
//      8 xmid = R(fp32) + acc -> bf16;  9 out = Rb(bf16) + acc -> fp32.
template<int EPI>
__global__ __launch_bounds__(512, 2)
void gemm256(const __hip_bfloat16* A, const __hip_bfloat16* Bt,
             void* Cout, const void* Rv,
             int K, int lda, int ldb, int ldc)
{
    int bx = blockIdx.x, by = blockIdx.y, bz = blockIdx.z;
    xcd_remap(bx, by, bz);

    const int tid  = threadIdx.x;
    const int lane = tid & 63, wave = tid >> 6;
    const int l15  = lane & 15, l4 = lane >> 4;
    const int wr   = wave >> 2, wc = wave & 3;
    const int m0   = by * 256, n0 = bx * 256;

    __shared__ __align__(16) char lds_[131072];
    char* lds  = lds_;
    char* ldsw = lds_ + wave * 1024;

    const int NT = K >> 6;

    const int offk0 = l15 * 128 + (((l4)     ^ (l15 & 7)) << 4);
    const int offk1 = l15 * 128 + (((4 + l4) ^ (l15 & 7)) << 4);
    const int wrb = wr * 16384, wcb = wc * 8192;

    const int rowq  = tid >> 3;
    const int sslot = (tid & 7) ^ (rowq & 7);
    const int aoff  = (m0 + rowq) * lda + sslot * 8;
    const int boff  = (n0 + rowq) * ldb + sslot * 8;

    f32x4 acc[8][4];
#pragma unroll
    for (int i = 0; i < 8; ++i)
#pragma unroll
        for (int j = 0; j < 4; ++j) acc[i][j] = (f32x4){0.f, 0.f, 0.f, 0.f};

    STB(0, 0, 0); STB(0, 1, 0); STA(0, 0, 0); STA(0, 1, 0);
    STB(1, 0, 1); STB(1, 1, 1); STA(1, 0, 1); STA(1, 1, 1);
    asm volatile("s_waitcnt vmcnt(8)" ::: "memory");
    __builtin_amdgcn_s_barrier();

    int t = 0;
    for (; t < NT - 2; ++t) TILE_BODY(t, true);
    for (; t < NT; ++t)     TILE_BODY(t, false);

    asm volatile("s_waitcnt vmcnt(0)" ::: "memory");

#pragma unroll
    for (int mf = 0; mf < 8; ++mf) {
        const int rbase = m0 + wr * 128 + mf * 16 + l4 * 4;
#pragma unroll
        for (int nf = 0; nf < 4; ++nf) {
            const int col = n0 + wc * 64 + nf * 16 + l15;
#pragma unroll
            for (int r = 0; r < 4; ++r) {
                const float v = acc[mf][nf][r];
                const int row = rbase + r;
                if constexpr (EPI == 5) {
                    ((__hip_bfloat16*)Cout)[((long long)(row >> 11) * C_DIM + col) * T_DIM
                                            + (row & 2047)] = __float2bfloat16(v);
                } else {
                    const long long idx = (long long)row * ldc + col;
                    if constexpr (EPI == 0) {
                        ((__hip_bfloat16*)Cout)[idx] = __float2bfloat16(v);
                    } else if constexpr (EPI == 3) {
                        const float s = v / (1.f + __expf(-v));
                        ((__hip_bfloat16*)Cout)[idx] = __float2bfloat16(s);
                    } else if constexpr (EPI == 8) {
                        const float xr = ((const float*)Rv)[idx];
                        ((__hip_bfloat16*)Cout)[idx] = __float2bfloat16(v + xr);
                    } else { // EPI == 9
                        const float xr =
                            __bfloat162float(((const __hip_bfloat16*)Rv)[idx]);
                        ((float*)Cout)[idx] = v + xr;
                    }
                }
            }
        }
    }
}

// ===========================================================================
// 256x256, 32x32x16 fragments (q kernel).
// ===========================================================================
__global__ __launch_bounds__(512, 2)
void gemm256_w32(const __hip_bfloat16* A, const __hip_bfloat16* Bt,
                 void* Cout, int K, int lda, int ldb, int ldc)
{
    int bx = blockIdx.x, by = blockIdx.y, bz = blockIdx.z;
    xcd_remap(bx, by, bz);

    const int tid  = threadIdx.x;
    const int lane = tid & 63, wave = tid >> 6;
    const int l31  = lane & 31, l5 = lane >> 5;
    const int wr   = wave >> 2, wc = wave & 3;
    const int m0   = by * 256, n0 = bx * 256;

    __shared__ __align__(16) char lds_[131072];
    char* lds  = lds_;
    char* ldsw = lds_ + wave * 1024;

    const int NT = K >> 6;

    const int rowq  = tid >> 3;
    const int sslot = (tid & 7) ^ (rowq & 7);
    const int aoff  = (m0 + rowq) * lda + sslot * 8;
    const int boff  = (n0 + rowq) * ldb + sslot * 8;

    f32x16 acc[4][2];
#pragma unroll
    for (int i = 0; i < 4; ++i)
#pragma unroll
        for (int j = 0; j < 2; ++j)
#pragma unroll
            for (int e = 0; e < 16; ++e) acc[i][j][e] = 0.f;

    const int arowl = l31 & 7;

    STB(0, 0, 0); STB(0, 1, 0); STA(0, 0, 0); STA(0, 1, 0);
    STB(1, 0, 1); STB(1, 1, 1); STA(1, 0, 1); STA(1, 1, 1);
    asm volatile("s_waitcnt vmcnt(8)" ::: "memory");
    __builtin_amdgcn_s_barrier();

    for (int t = 0; t < NT; ++t) {
        const int buf_ = t & 1;
        bf16x8 aR[4][4], bR[2][4];
#pragma unroll
        for (int mf = 0; mf < 4; ++mf) {
            const int arow = wr * 128 + mf * 32 + l31;
            const char* p_ = lds + buf_ * 32768 + arow * 128;
#pragma unroll
            for (int ks = 0; ks < 4; ++ks)
                aR[mf][ks] = *(const bf16x8*)(p_ + ((((ks << 1) | l5) ^ arowl) << 4));
        }
#pragma unroll
        for (int nf = 0; nf < 2; ++nf) {
            const int bcol = wc * 64 + nf * 32 + l31;
            const char* p_ = lds + 65536 + buf_ * 32768 + bcol * 128;
#pragma unroll
            for (int ks = 0; ks < 4; ++ks)
                bR[nf][ks] = *(const bf16x8*)(p_ + ((((ks << 1) | l5) ^ arowl) << 4));
        }
        __builtin_amdgcn_s_setprio(1);
#pragma unroll
        for (int mf = 0; mf < 4; ++mf)
#pragma unroll
            for (int nf = 0; nf < 2; ++nf)
#pragma unroll
                for (int ks = 0; ks < 4; ++ks)
                    acc[mf][nf] = __builtin_amdgcn_mfma_f32_32x32x16_bf16(
                        aR[mf][ks], bR[nf][ks], acc[mf][nf], 0, 0, 0);
        __builtin_amdgcn_s_setprio(0);
        asm volatile("s_waitcnt lgkmcnt(0)" ::: "memory");
        asm volatile("s_waitcnt vmcnt(0)" ::: "memory");
        __builtin_amdgcn_s_barrier();
        if (t + 2 < NT) {
            STB(buf_, 0, t + 2); STB(buf_, 1, t + 2);
            STA(buf_, 0, t + 2); STA(buf_, 1, t + 2);
        }
    }
    asm volatile("s_waitcnt vmcnt(0)" ::: "memory");

    // C/D: col = lane&31, row = (reg&3) + 8*(reg>>2) + 4*(lane>>5)
#pragma unroll
    for (int mf = 0; mf < 4; ++mf)
#pragma unroll
        for (int nf = 0; nf < 2; ++nf) {
            const int col = n0 + wc * 64 + nf * 32 + l31;
#pragma unroll
            for (int reg = 0; reg < 16; ++reg) {
                const int row = m0 + wr * 128 + mf * 32
                              + (reg & 3) + 8 * (reg >> 2) + 4 * l5;
                ((__hip_bfloat16*)Cout)[(long long)row * ldc + col] =
                    __float2bfloat16(acc[mf][nf][reg]);
            }
        }
}

// ===========================================================================
// 128x128 kernel: BK=32, 4 waves, dbuf 32 KiB, 4-chunk swz (S and AV).
// EPI: 0 bf16; 4 bf16*scale.  CMODE: 1 causal skip; 2 causal K clip.
// ===========================================================================
template<int EPI, int CMODE>
__global__ __launch_bounds__(256)
void gemm128(const __hip_bfloat16* A, const __hip_bfloat16* Bt,
             void* Cout, int K, int lda, int ldb, int ldc,
             long long sA, long long sB, long long sC, float scale)
{
    int bx = blockIdx.x, by = blockIdx.y, bz = blockIdx.z;
    xcd_remap(bx, by, bz);
    if constexpr (CMODE == 1) { if (bx > by) return; }

    const int tid  = threadIdx.x;
    const int lane = tid & 63, wave = tid >> 6;
    const int l15  = lane & 15, l4 = lane >> 4;
    const int wr   = wave >> 1, wc = wave & 1;
    const int m0   = by * 128, n0 = bx * 128;
    const int z    = bz;

    A  += (long long)z * sA;
    Bt += (long long)z * sB;

    __shared__ __align__(16) short As[2][128 * 32];
    __shared__ __align__(16) short Bs[2][128 * 32];

    int kmax = K;
    if constexpr (CMODE == 2) { int km = m0 + 128; kmax = km < K ? km : K; }

    f32x4 acc[4][4];
#pragma unroll
    for (int i = 0; i < 4; ++i)
#pragma unroll
        for (int j = 0; j < 4; ++j) acc[i][j] = (f32x4){0.f, 0.f, 0.f, 0.f};

    const int srow  = wave * 32 + (lane >> 2);
    const int sbyte = (((lane & 3) ^ ((lane >> 2) & 3))) << 4;
    const char* Ag = (const char*)(A  + (long long)(m0 + srow) * lda) + sbyte;
    const char* Bg = (const char*)(Bt + (long long)(n0 + srow) * ldb) + sbyte;
    const long long astep = (long long)16 * lda * 2;
    const long long bstep = (long long)16 * ldb * 2;
    char* AsW[2] = {(char*)As[0] + wave * 2048, (char*)As[1] + wave * 2048};
    char* BsW[2] = {(char*)Bs[0] + wave * 2048, (char*)Bs[1] + wave * 2048};

    auto stage = [&](int buf, int k0) {
        const char* ag = Ag + (long long)k0 * 2;
        const char* bg = Bg + (long long)k0 * 2;
        gload_lds16(ag,         AsW[buf]);
        gload_lds16(ag + astep, AsW[buf] + 1024);
        gload_lds16(bg,         BsW[buf]);
        gload_lds16(bg + bstep, BsW[buf] + 1024);
    };

    const int cs16 = ((l4 ^ (l15 & 3)) << 4);

    stage(0, 0);
    __syncthreads();

    for (int k0 = 0; k0 < kmax; k0 += 32) {
        const int buf = (k0 >> 5) & 1;
        if (k0 + 32 < kmax) stage(buf ^ 1, k0 + 32);

        const char* Ac = (const char*)As[buf];
        const char* Bc = (const char*)Bs[buf];
        bf16x8 af[4], bfr[4];
#pragma unroll
        for (int mi = 0; mi < 4; ++mi) {
            int row = wr * 64 + mi * 16 + l15;
            af[mi] = *(const bf16x8*)(Ac + row * 64 + cs16);
        }
#pragma unroll
        for (int ni = 0; ni < 4; ++ni) {
            int col = wc * 64 + ni * 16 + l15;
            bfr[ni] = *(const bf16x8*)(Bc + col * 64 + cs16);
        }
#pragma unroll
        for (int mi = 0; mi < 4; ++mi)
#pragma unroll
            for (int ni = 0; ni < 4; ++ni)
                acc[mi][ni] = __builtin_amdgcn_mfma_f32_16x16x32_bf16(
                    af[mi], bfr[ni], acc[mi][ni], 0, 0, 0);

        __syncthreads();
    }

    const long long cbase = (long long)z * sC;
#pragma unroll
    for (int mi = 0; mi < 4; ++mi) {
        const int rbase = m0 + wr * 64 + mi * 16 + l4 * 4;
#pragma unroll
        for (int ni = 0; ni < 4; ++ni) {
            const int col = n0 + wc * 64 + ni * 16 + l15;
#pragma unroll
            for (int r = 0; r < 4; ++r) {
                const long long idx = cbase + (long long)(rbase + r) * ldc + col;
                const float v = acc[mi][ni][r];
                if constexpr (EPI == 0) {
                    ((__hip_bfloat16*)Cout)[idx] = __float2bfloat16(v);
                } else { // EPI == 4
                    ((__hip_bfloat16*)Cout)[idx] = __float2bfloat16(v * scale);
                }
            }
        }
    }
}

// ---------------------------------------------------------------------------
// RMSNorm: one block per row of C_DIM; input fp32 or bf16, output bf16.
// ---------------------------------------------------------------------------
template<bool BF16IN>
__global__ __launch_bounds__(256)
void rmsnorm_kernel(const void* __restrict__ xin, const float* __restrict__ g,
                    __hip_bfloat16* __restrict__ out)
{
    const long long row = blockIdx.x;
    const int tid = threadIdx.x;
    float e0, e1, e2, e3;
    if constexpr (BF16IN) {
        const ushort4 u = ((const ushort4*)((const __hip_bfloat16*)xin + row * C_DIM))[tid];
        e0 = __uint_as_float((unsigned)u.x << 16);
        e1 = __uint_as_float((unsigned)u.y << 16);
        e2 = __uint_as_float((unsigned)u.z << 16);
        e3 = __uint_as_float((unsigned)u.w << 16);
    } else {
        const float4 v = ((const float4*)((const float*)xin + row * C_DIM))[tid];
        e0 = v.x; e1 = v.y; e2 = v.z; e3 = v.w;
    }
    float ss = e0 * e0 + e1 * e1 + e2 * e2 + e3 * e3;
#pragma unroll
    for (int off = 32; off; off >>= 1) ss += __shfl_xor(ss, off);
    __shared__ float red[4];
    if ((tid & 63) == 0) red[tid >> 6] = ss;
    __syncthreads();
    ss = red[0] + red[1] + red[2] + red[3];
    const float sc = rsqrtf(ss * (1.0f / C_DIM) + 1e-6f);
    const float4 gv = ((const float4*)g)[tid];
    ushort4 u;
    u.x = f2bf_bits(e0 * sc * gv.x);
    u.y = f2bf_bits(e1 * sc * gv.y);
    u.z = f2bf_bits(e2 * sc * gv.z);
    u.w = f2bf_bits(e3 * sc * gv.w);
    *(ushort4*)(out + row * C_DIM + tid * 4) = u;
}

// ---------------------------------------------------------------------------
// Causal softmax, IN PLACE on bf16 S [B,T,T], triangular (cols < AV K-clip).
// ---------------------------------------------------------------------------
__global__ __launch_bounds__(256)
void softmax_causal(__hip_bfloat16* __restrict__ SP)
{
    const int i = blockIdx.x, b = blockIdx.y;
    __hip_bfloat16* row = SP + ((long long)b * T_DIM + i) * T_DIM;
    const int tid = threadIdx.x;
    const int jbase = tid * 8;
    const int kmax = ((i >> 7) + 1) << 7;
    const bool act = jbase < kmax;

    float v[8];
    if (act) {
        uint4 raw = ((const uint4*)row)[tid];
        const unsigned w[4] = {raw.x, raw.y, raw.z, raw.w};
#pragma unroll
        for (int c = 0; c < 4; ++c) {
            v[2 * c]     = __uint_as_float(w[c] << 16);
            v[2 * c + 1] = __uint_as_float(w[c] & 0xFFFF0000u);
        }
#pragma unroll
        for (int e = 0; e < 8; ++e)
            if (jbase + e > i) v[e] = -1e30f;
    } else {
#pragma unroll
        for (int e = 0; e < 8; ++e) v[e] = -1e30f;
    }

    float m = v[0];
#pragma unroll
    for (int e = 1; e < 8; ++e) m = fmaxf(m, v[e]);
#pragma unroll
    for (int off = 32; off; off >>= 1) m = fmaxf(m, __shfl_xor(m, off));
    __shared__ float redm[4], reds[4];
    if ((tid & 63) == 0) redm[tid >> 6] = m;
    __syncthreads();
    m = fmaxf(fmaxf(redm[0], redm[1]), fmaxf(redm[2], redm[3]));

    float e8[8];
    float s = 0.f;
#pragma unroll
    for (int e = 0; e < 8; ++e) { e8[e] = __expf(v[e] - m); s += e8[e]; }
#pragma unroll
    for (int off = 32; off; off >>= 1) s += __shfl_xor(s, off);
    if ((tid & 63) == 0) reds[tid >> 6] = s;
    __syncthreads();
    s = reds[0] + reds[1] + reds[2] + reds[3];
    const float inv = 1.f / s;

    if (act) {
        uint4 outw;
        unsigned o[4];
#pragma unroll
        for (int c = 0; c < 4; ++c) {
            unsigned lo = f2bf_bits(e8[2 * c] * inv);
            unsigned hi = f2bf_bits(e8[2 * c + 1] * inv);
            o[c] = lo | (hi << 16);
        }
        outw.x = o[0]; outw.y = o[1]; outw.z = o[2]; outw.w = o[3];
        ((uint4*)row)[tid] = outw;
    }
}

// ---------------------------------------------------------------------------
// Weight cast + transpose: in fp32 [K,N] -> out bf16 [N,K]
// ---------------------------------------------------------------------------
__global__ __launch_bounds__(256)
void wcast_t(const float* __restrict__ in, __hip_bfloat16* __restrict__ out,
             int K, int N)
{
    __shared__ float t[32][33];
    const int n0 = blockIdx.x * 32, k0 = blockIdx.y * 32;
    const int tx = threadIdx.x, ty = threadIdx.y;
#pragma unroll
    for (int r = ty; r < 32; r += 8)
        t[r][tx] = in[(long long)(k0 + r) * N + n0 + tx];
    __syncthreads();
#pragma unroll
    for (int r = ty; r < 32; r += 8)
        out[(long long)(n0 + r) * K + k0 + tx] = __float2bfloat16(t[tx][r]);
}

// ---------------------------------------------------------------------------
extern "C" void kernel_launch(void* const* d_in, const int* in_sizes, int n_in,
                              void* d_out, int out_size, void* d_ws, size_t ws_size,
                              hipStream_t stream)
{
    const float* x      = (const float*)d_in[0];
    const float* w_qkv  = (const float*)d_in[1];
    const float* w_proj = (const float*)d_in[2];
    const float* w1     = (const float*)d_in[3];
    const float* w2     = (const float*)d_in[4];
    const float* g1     = (const float*)d_in[5];
    const float* g2     = (const float*)d_in[6];
    float* out = (float*)d_out;
    char* ws = (char*)d_ws;

    const size_t SP_off = 0;                       // S/P bf16 [8,2048,2048] 64MiB
    const size_t h_off  = 0;                       // h bf16 (before S exists)
    const size_t u_off  = 0;                       // u bf16 (after P dead)
    const size_t q_off  = 67108864ull;             // q bf16 -> h2
    const size_t k_off  = 100663296ull;            // k bf16 -> av
    const size_t vT_off = 134217728ull;            // vT bf16 -> x_mid bf16 (after AV)
    const size_t wq_off = 167772160ull;            // 6.29MB
    const size_t wp_off = wq_off + 6291456ull;     // 2.10MB
    const size_t w1_off = wp_off + 2097152ull;     // 4.19MB
    const size_t w2_off = w1_off + 4194304ull;     // 4.19MB
    const size_t NEED   = w2_off + 4194304ull;     // 176 MiB

    if (ws_size < NEED) return;  // guard: fail absmax instead of faulting

    auto bf = [&](size_t off) { return (__hip_bfloat16*)(ws + off); };

    // 1. weights -> bf16 [N,K]
    wcast_t<<<dim3(96, 32), dim3(32, 8), 0, stream>>>(w_qkv,  bf(wq_off), 1024, 3072);
    wcast_t<<<dim3(32, 32), dim3(32, 8), 0, stream>>>(w_proj, bf(wp_off), 1024, 1024);
    wcast_t<<<dim3(64, 32), dim3(32, 8), 0, stream>>>(w1,     bf(w1_off), 1024, 2048);
    wcast_t<<<dim3(32, 64), dim3(32, 8), 0, stream>>>(w2,     bf(w2_off), 2048, 1024);

    // 2. h = rmsnorm(x, g1)
    rmsnorm_kernel<false><<<16384, 256, 0, stream>>>(x, g1, bf(h_off));

    // 3a. q = h @ Wq   [32x32x16 core]
    gemm256_w32<<<dim3(4, 64, 1), 512, 0, stream>>>(
        bf(h_off), bf(wq_off), bf(q_off), 1024, 1024, 1024, 1024);
    // 3b. k = h @ Wk
    gemm256<0><<<dim3(4, 64, 1), 512, 0, stream>>>(
        bf(h_off), bf(wq_off) + 1024 * 1024, bf(k_off), nullptr,
        1024, 1024, 1024, 1024);
    // 3c. vT = (h @ Wv)^T
    gemm256<5><<<dim3(4, 64, 1), 512, 0, stream>>>(
        bf(h_off), bf(wq_off) + 2 * 1024 * 1024, bf(vT_off), nullptr,
        1024, 1024, 1024, 2048);

    // 4. S = q @ k^T * 1/32  (128-tile, causal block skip)
    gemm128<4, 1><<<dim3(16, 16, 8), 256, 0, stream>>>(
        bf(q_off), bf(k_off), bf(SP_off),
        1024, 1024, 1024, 2048,
        (long long)T_DIM * C_DIM, (long long)T_DIM * C_DIM, (long long)T_DIM * T_DIM,
        0.03125f);

    // 5. P = causal softmax(S), in place, triangular
    softmax_causal<<<dim3(2048, 8), 256, 0, stream>>>(bf(SP_off));

    // 6. av = P @ V  (128-tile, K clipped at diagonal)
    gemm128<0, 2><<<dim3(8, 16, 8), 256, 0, stream>>>(
        bf(SP_off), bf(vT_off), bf(k_off) /*av*/,
        2048, 2048, 2048, 1024,
        (long long)T_DIM * T_DIM, (long long)C_DIM * T_DIM, (long long)T_DIM * C_DIM,
        1.f);

    // 7. x_mid(bf16) = x(fp32) + av @ w_proj   (-> vT region, vT dead)
    gemm256<8><<<dim3(4, 64, 1), 512, 0, stream>>>(
        bf(k_off) /*av*/, bf(wp_off), bf(vT_off) /*x_mid*/, x,
        1024, 1024, 1024, 1024);

    // 8. h2 = rmsnorm(x_mid bf16, g2)   (-> q region)
    rmsnorm_kernel<true><<<16384, 256, 0, stream>>>(bf(vT_off), g2, bf(q_off));

    // 9. u = silu(h2 @ w1)   (-> SP region, dead)
    gemm256<3><<<dim3(8, 64, 1), 512, 0, stream>>>(
        bf(q_off), bf(w1_off), bf(u_off), nullptr,
        1024, 1024, 1024, 2048);

    // 10. out(fp32) = x_mid(bf16) + u @ w2
    gemm256<9><<<dim3(4, 64, 1), 512, 0, stream>>>(
        bf(u_off), bf(w2_off), out, bf(vT_off) /*x_mid*/,
        2048, 2048, 2048, 1024);
}